// Round 5
// baseline (137.469 us; speedup 1.0000x reference)
//
#include <hip/hip_runtime.h>
#include <hip/hip_bf16.h>

#define D_FEAT 256
#define BT 256      // output tile (M and N)
#define BK 64       // K-step

typedef float f32x4 __attribute__((ext_vector_type(4)));
typedef short bf16x8 __attribute__((ext_vector_type(8)));

// round-to-nearest-even f32 -> bf16 bits
__device__ __forceinline__ unsigned short f2bf(float f) {
  unsigned int u = __float_as_uint(f);
  u += 0x7fffu + ((u >> 16) & 1u);
  return (unsigned short)(u >> 16);
}

// raw v_exp_f32 (base-2). Input always <= 0 in fast path.
__device__ __forceinline__ float exp2r(float x) {
  return __builtin_amdgcn_exp2f(x);
}

// Convert BOTH input matrices to bf16, compute exact f32 row sq-norms,
// and zero the 3 global accumulators. One wave per row.
__global__ void prep_kernel(const float* __restrict__ X,
                            const float* __restrict__ Y,
                            unsigned short* __restrict__ Xb,
                            unsigned short* __restrict__ Yb,
                            float* __restrict__ xsq, float* __restrict__ ysq,
                            double* __restrict__ accum, int N, int M) {
  if (blockIdx.x == 0 && threadIdx.x < 3) accum[threadIdx.x] = 0.0;
  int row = blockIdx.x * 4 + (threadIdx.x >> 6);
  int lane = threadIdx.x & 63;
  if (row >= N + M) return;
  const float* src; unsigned short* dst; float* sq; int r;
  if (row < N) { src = X; dst = Xb; sq = xsq; r = row; }
  else         { src = Y; dst = Yb; sq = ysq; r = row - N; }
  float4 v = reinterpret_cast<const float4*>(src)[r * (D_FEAT / 4) + lane];
  float s = v.x * v.x + v.y * v.y + v.z * v.z + v.w * v.w;
  ushort4 o;
  o.x = f2bf(v.x); o.y = f2bf(v.y); o.z = f2bf(v.z); o.w = f2bf(v.w);
  reinterpret_cast<ushort4*>(dst)[r * (D_FEAT / 4) + lane] = o;
#pragma unroll
  for (int off = 32; off > 0; off >>= 1) s += __shfl_down(s, off);
  if (lane == 0) sq[r] = s;
}

// 256x256-tile fused pair kernel, 8 waves, counted-vmcnt pipeline.
// No __syncthreads in the K-loop (it would drain vmcnt(0)); raw s_barrier
// + per-wave counted vmcnt keep 8-16 loads in flight across barriers.
__global__ __launch_bounds__(512, 2)
void mmd_pair_kernel(const unsigned short* __restrict__ Xb,
                     const unsigned short* __restrict__ Yb,
                     const float* __restrict__ xsq,
                     const float* __restrict__ ysq,
                     double* __restrict__ accum,
                     int ntx, int nty, int num_xy, int num_tri_x) {
  __shared__ unsigned short As[2][BT * BK];   // 2 x 32 KB
  __shared__ unsigned short Bs[2][BT * BK];   // 2 x 32 KB
  __shared__ float wsum[8];

  // XCD-chunked bijective remap (m204): XCD x gets a contiguous range.
  int grid = gridDim.x;
  int q8 = grid >> 3, r8 = grid & 7;
  int xcd = blockIdx.x & 7, slot = blockIdx.x >> 3;
  int l = (xcd < r8) ? (xcd * (q8 + 1) + slot)
                     : (r8 * (q8 + 1) + (xcd - r8) * q8 + slot);

  const unsigned short *Ap, *Bp;
  const float *asq, *bsq;
  int ti, tj, accIdx;
  float wt = 1.0f;
  bool maskDiag = false;

  if (l < num_xy) {
    ti = l / nty; tj = l - ti * nty;
    Ap = Xb; Bp = Yb; asq = xsq; bsq = ysq; accIdx = 2;
  } else {
    int t = l - num_xy, nt;
    if (t < num_tri_x) {
      nt = ntx; Ap = Xb; Bp = Xb; asq = xsq; bsq = xsq; accIdx = 0;
    } else {
      t -= num_tri_x;
      nt = nty; Ap = Yb; Bp = Yb; asq = ysq; bsq = ysq; accIdx = 1;
    }
    ti = 0;
    while (t >= nt - ti) { t -= nt - ti; ++ti; }  // upper-tri decode, ti<=tj
    tj = ti + t;
    if (ti == tj) maskDiag = true; else wt = 2.0f;
  }

  int tid = threadIdx.x;
  int wid = tid >> 6, lane = tid & 63;
  int wm = wid >> 2, wn = wid & 3;          // 2x4 wave grid; 128x64 per wave

  f32x4 acc[8][4];
#pragma unroll
  for (int m = 0; m < 8; ++m)
#pragma unroll
    for (int n = 0; n < 4; ++n) acc[m][n] = (f32x4){0.f, 0.f, 0.f, 0.f};

  const char* Abase = (const char*)Ap + (size_t)ti * BT * (D_FEAT * 2);
  const char* Bbase = (const char*)Bp + (size_t)tj * BT * (D_FEAT * 2);
  // staging geometry: chunk = 1KB = 8 rows x 128B; lane covers 16B.
  // LDS dest linear; source col-byte pre-swizzled (involution with read XOR).
  int srow = lane >> 3;
  int ssw = ((lane & 7) * 16) ^ (srow << 4);

  // stage K-tile kt into buffer b: 4 A-chunks + 4 B-chunks per wave (8 loads)
  auto stage = [&](int kt, int b) {
#pragma unroll
    for (int q = 0; q < 4; ++q) {
      int c = wid * 4 + q;                  // chunk 0..31 -> rows c*8..c*8+7
      size_t roff = (size_t)(c * 8 + srow) * (D_FEAT * 2) + kt * (BK * 2) + ssw;
      __builtin_amdgcn_global_load_lds(
          (const __attribute__((address_space(1))) unsigned int*)(Abase + roff),
          (__attribute__((address_space(3))) unsigned int*)((char*)As[b] + c * 1024),
          16, 0, 0);
      __builtin_amdgcn_global_load_lds(
          (const __attribute__((address_space(1))) unsigned int*)(Bbase + roff),
          (__attribute__((address_space(3))) unsigned int*)((char*)Bs[b] + c * 1024),
          16, 0, 0);
    }
  };

  // prologue: kt0 -> buf0, kt1 -> buf1; wait kt0 landed (kt1's 8 in flight)
  stage(0, 0);
  stage(1, 1);
  asm volatile("s_waitcnt vmcnt(8)" ::: "memory");
  __builtin_amdgcn_s_barrier();

#pragma unroll
  for (int kt = 0; kt < 4; ++kt) {
    const int b = kt & 1;
    const char* Ab = (const char*)As[b];
    const char* Bb = (const char*)Bs[b];
#pragma unroll
    for (int kk = 0; kk < 2; ++kk) {
      bf16x8 af[8];
      int colb = kk * 64 + (lane >> 4) * 16;
#pragma unroll
      for (int m = 0; m < 8; ++m) {
        int rr = wm * 128 + m * 16 + (lane & 15);
        af[m] = *(const bf16x8*)(Ab + rr * 128 + (colb ^ ((rr & 7) << 4)));
      }
#pragma unroll
      for (int qn = 0; qn < 2; ++qn) {
        int rr0 = wn * 64 + (qn * 2 + 0) * 16 + (lane & 15);
        bf16x8 bf0 = *(const bf16x8*)(Bb + rr0 * 128 + (colb ^ ((rr0 & 7) << 4)));
        int rr1 = wn * 64 + (qn * 2 + 1) * 16 + (lane & 15);
        bf16x8 bf1 = *(const bf16x8*)(Bb + rr1 * 128 + (colb ^ ((rr1 & 7) << 4)));
        __builtin_amdgcn_s_setprio(1);
#pragma unroll
        for (int m = 0; m < 8; ++m) {
          acc[m][qn * 2 + 0] = __builtin_amdgcn_mfma_f32_16x16x32_bf16(
              af[m], bf0, acc[m][qn * 2 + 0], 0, 0, 0);
          acc[m][qn * 2 + 1] = __builtin_amdgcn_mfma_f32_16x16x32_bf16(
              af[m], bf1, acc[m][qn * 2 + 1], 0, 0, 0);
        }
        __builtin_amdgcn_s_setprio(0);
        __builtin_amdgcn_s_barrier();
      }
    }
    // boundary: buf b fully consumed by all waves (phase barrier above).
    if (kt < 2) {
      stage(kt + 2, b);                     // refill just-freed buffer
      // wait: kt+1 fully landed; kt+2's 8 loads allowed in flight
      asm volatile("s_waitcnt vmcnt(8)" ::: "memory");
      __builtin_amdgcn_s_barrier();
    } else if (kt == 2) {
      asm volatile("s_waitcnt vmcnt(0)" ::: "memory");  // kt3 landed
      __builtin_amdgcn_s_barrier();
    }
  }

  // epilogue: d2 = |x|^2 + |y|^2 - 2*dot; 5-bandwidth gaussian sum.
  // exp(c*d2) = exp2(d2 * c*log2(e)), c = -1/(2*bw^2).
  const float C0 = (float)(-18.033688010972094);   // bw 0.2
  const float C1 = (float)(-2.8853900817555354);   // bw 0.5
  const float C2 = (float)(-0.7213475204388839);   // bw 1.0
  const float C3 = (float)(-0.18033688010972097);  // bw 2.0
  const float C4 = (float)(-0.028853900817555354); // bw 5.0
  // d2 > 210 -> C0..C2 terms are exactly 0 in f32 (below denorm min);
  // off-diagonal d2 ~ 512 +- 45, so slow path is essentially never taken.

  int rbase = ti * BT + wm * 128 + (lane >> 4) * 4;
  int cbase = tj * BT + wn * 64 + (lane & 15);
  float xsr[8][4], ysc[4];
#pragma unroll
  for (int m = 0; m < 8; ++m)
#pragma unroll
    for (int j = 0; j < 4; ++j) xsr[m][j] = asq[rbase + m * 16 + j];
#pragma unroll
  for (int n = 0; n < 4; ++n) ysc[n] = bsq[cbase + n * 16];

  float sum = 0.f;
#pragma unroll
  for (int m = 0; m < 8; ++m)
#pragma unroll
    for (int n = 0; n < 4; ++n) {
      float tv[4], es[4];
#pragma unroll
      for (int j = 0; j < 4; ++j)
        tv[j] = fmaf(-2.0f, acc[m][n][j], xsr[m][j] + ysc[n]);
      float tmin = fminf(fminf(tv[0], tv[1]), fminf(tv[2], tv[3]));
#pragma unroll
      for (int j = 0; j < 4; ++j)
        es[j] = exp2r(tv[j] * C3) + exp2r(tv[j] * C4);
      if (__any(tmin < 210.0f)) {
#pragma unroll
        for (int j = 0; j < 4; ++j) {
          float d2 = fmaxf(tv[j], 0.0f);
          es[j] += exp2r(d2 * C0) + exp2r(d2 * C1) + exp2r(d2 * C2);
        }
      }
      if (maskDiag) {
#pragma unroll
        for (int j = 0; j < 4; ++j)
          if ((rbase + m * 16 + j) == (cbase + n * 16)) es[j] = 0.0f;
      }
      sum += (es[0] + es[1]) + (es[2] + es[3]);
    }

#pragma unroll
  for (int off = 32; off > 0; off >>= 1) sum += __shfl_down(sum, off);
  if (lane == 0) wsum[wid] = sum;
  __syncthreads();
  if (tid == 0) {
    double t = (double)(((wsum[0] + wsum[1]) + (wsum[2] + wsum[3])) +
                        ((wsum[4] + wsum[5]) + (wsum[6] + wsum[7]))) *
               (double)wt;
    atomicAdd(&accum[accIdx], t);
  }
}

__global__ void finalize_kernel(const double* __restrict__ accum,
                                float* __restrict__ out, int N, int M) {
  double dN = (double)N, dM = (double)M;
  double v = accum[0] / (5.0 * dN * dN) + accum[1] / (5.0 * dM * dM)
           - 2.0 * accum[2] / (5.0 * dN * dM) + 1.0 / dN + 1.0 / dM;
  out[0] = (float)v;
}

extern "C" void kernel_launch(void* const* d_in, const int* in_sizes, int n_in,
                              void* d_out, int out_size, void* d_ws, size_t ws_size,
                              hipStream_t stream) {
  const float* s = (const float*)d_in[0];
  const float* t = (const float*)d_in[1];
  int N = in_sizes[0] / D_FEAT;
  int M = in_sizes[1] / D_FEAT;

  char* ws = (char*)d_ws;
  unsigned short* Xb = (unsigned short*)ws;
  unsigned short* Yb = Xb + (size_t)N * D_FEAT;
  float* xsq = (float*)(Yb + (size_t)M * D_FEAT);
  float* ysq = xsq + N;
  double* accum = (double*)(((uintptr_t)(ysq + M) + 15) & ~(uintptr_t)15);

  prep_kernel<<<(N + M + 3) / 4, 256, 0, stream>>>(s, t, Xb, Yb, xsq, ysq,
                                                   accum, N, M);

  int ntx = N / BT, nty = M / BT;
  int num_xy = ntx * nty;
  int num_tri_x = ntx * (ntx + 1) / 2;
  int num_tri_y = nty * (nty + 1) / 2;
  int grid = num_xy + num_tri_x + num_tri_y;
  mmd_pair_kernel<<<grid, 512, 0, stream>>>(Xb, Yb, xsq, ysq, accum,
                                            ntx, nty, num_xy, num_tri_x);
  finalize_kernel<<<1, 1, 0, stream>>>(accum, (float*)d_out, N, M);
}